// Round 6
// baseline (45.495 us; speedup 1.0000x reference)
//
#include <hip/hip_runtime.h>

#define NBINS 128
#define NFREQ 64
#define HDIM 128
#define NQ 16384
#define EPSF 1e-8f

// d_ws layout:
//   [0, 128 KiB)   : probeT — float4 {pr, pi, -softplus(w), mw} in (bq,fq)-tiles:
//                    index (bq*8+fq)*128 + bi*8 + fi   (bq: 8 chunks of 16 bins,
//                    fq: 8 chunks of 8 freqs). Read via wave-uniform s_load.
//   [128 KiB, +4M) : QR plane  [f*NQ + q]  (normalized real)
//   next 4 MiB     : QI plane  [f*NQ + q]  (normalized imag)
//   next 4 MiB     : QM plane  [f*NQ + q]  (per-freq magnitude)
#define PT_OFF 0
#define QR_OFF (128 * 1024)
#define PLANE_BYTES ((size_t)NQ * NFREQ * 4)
#define QI_OFF (QR_OFF + PLANE_BYTES)
#define QM_OFF (QI_OFF + PLANE_BYTES)
#define WS_NEEDED (QM_OFF + PLANE_BYTES)

#define QN_BLOCKS (NQ / 64)                       // 256 blocks, 64 queries each
#define PACK_BLOCKS ((NBINS * NFREQ + 255) / 256) // 32 blocks

// ---------- Prologue: Q planes (blocks 0..255) + probe tiles (blocks 256..287) ----------
__global__ __launch_bounds__(256) void prologue6(
    const float* __restrict__ Q,
    const float* __restrict__ probes,
    const float* __restrict__ wraw,
    const float* __restrict__ mw,
    float4* __restrict__ probeT,
    float* __restrict__ QR, float* __restrict__ QI, float* __restrict__ QM) {
  const int blk = blockIdx.x;
  const int t = threadIdx.x;
  if (blk < QN_BLOCKS) {
    const int l = t & 3;                 // 4 lanes per query; lane l owns freqs [16l,16l+16)
    const int q = blk * 64 + (t >> 2);
    const float* qp = Q + (size_t)q * HDIM;
    float re[16], im[16];
    #pragma unroll
    for (int k = 0; k < 4; ++k) {
      *reinterpret_cast<float4*>(&re[k * 4]) =
          *reinterpret_cast<const float4*>(qp + 16 * l + k * 4);
      *reinterpret_cast<float4*>(&im[k * 4]) =
          *reinterpret_cast<const float4*>(qp + NFREQ + 16 * l + k * 4);
    }
    float s = 0.0f;
    #pragma unroll
    for (int k = 0; k < 16; ++k) {
      s = fmaf(re[k], re[k], s);
      s = fmaf(im[k], im[k], s);
    }
    s += __shfl_xor(s, 1, 4);
    s += __shfl_xor(s, 2, 4);
    const float inv = 1.0f / (__builtin_amdgcn_sqrtf(s) + EPSF);
    #pragma unroll
    for (int k = 0; k < 16; ++k) {
      const int f = 16 * l + k;
      const float qr = re[k] * inv;
      const float qi = im[k] * inv;
      const float qm = __builtin_amdgcn_sqrtf(fmaf(qr, qr, fmaf(qi, qi, EPSF)));
      QR[(size_t)f * NQ + q] = qr;   // 4x 64B segments per store inst — ok
      QI[(size_t)f * NQ + q] = qi;
      QM[(size_t)f * NQ + q] = qm;
    }
  } else {
    const int idx = (blk - QN_BLOCKS) * 256 + t;
    if (idx >= NBINS * NFREQ) return;
    const int b = idx >> 6;
    const int f = idx & 63;
    const float pr = probes[b * HDIM + f];
    const float pi = probes[b * HDIM + NFREQ + f];
    const float x = wraw[b * NFREQ + f];
    const float sp = fmaxf(x, 0.0f) + log1pf(expf(-fabsf(x)));  // stable softplus
    const float m = mw[b * NFREQ + f];
    const int tIdx = (b >> 4) * 8 + (f >> 3);
    probeT[tIdx * 128 + (b & 15) * 8 + (f & 7)] = make_float4(pr, pi, -sp, m);
  }
}

// ---------- Main: lane = QUERY; probe data via wave-uniform s_load (SGPR operands) ----------
// Inner loop has no LDS / no VMEM: avoids both the K$-miss wall (round 2/3) and the
// LDS broadcast-writeback wall (round 5, ~12cyc/b128 regardless of broadcast).
__global__ __launch_bounds__(512) void scorer6(
    const float4* __restrict__ probeT,
    const float* __restrict__ QR, const float* __restrict__ QI,
    const float* __restrict__ QM,
    const float* __restrict__ bias,
    float* __restrict__ out) {
  __shared__ float part[8][16][64];  // [fq][bi][lane(q)] — 32 KB, conflict-free
  const int t = threadIdx.x;
  const int lane = t & 63;
  const int fq = __builtin_amdgcn_readfirstlane(t >> 6);  // 0..7: freq chunk of 8
  const int qc = blockIdx.x >> 3;    // 0..255: query chunk of 64
  const int bq = blockIdx.x & 7;     // 0..7 : bin chunk of 16
  const int q = qc * 64 + lane;

  // Per-lane query data: 24 coalesced dword loads (256B/inst), once per wave
  float qr[8], qi[8], qm[8];
  #pragma unroll
  for (int j = 0; j < 8; ++j) {
    const size_t fo = (size_t)(fq * 8 + j) * NQ + q;
    qr[j] = QR[fo];
    qi[j] = QI[fo];
    qm[j] = QM[fo];
  }

  // Wave's probe tile: 16 bins x 8 freqs x float4 = 2 KB, wave-uniform -> s_load
  const float4* tile = probeT + (bq * 8 + fq) * 128;

  #pragma unroll 4
  for (int bi = 0; bi < 16; ++bi) {
    float a = 0.0f;
    #pragma unroll
    for (int j = 0; j < 8; ++j) {
      const float4 c = tile[bi * 8 + j];   // SGPRs; 1 SGPR per VALU inst below
      float er = c.x - qr[j];
      float ei = c.y - qi[j];
      float d2 = fmaf(er, er, EPSF);
      d2 = fmaf(ei, ei, d2);
      float d = __builtin_amdgcn_sqrtf(d2);
      a = fmaf(d, c.z, a);
      a = fmaf(qm[j], c.w, a);
    }
    part[fq][bi][lane] = a;   // b32, lane-consecutive, conflict-free
  }
  __syncthreads();

  // Combine 8 freq-chunks; 512 threads cover 64q x 16b outputs (2 each)
  const int qe = t >> 3;       // 0..63
  const int k = t & 7;         // bi pair = {2k, 2k+1}
  float s0 = 0.0f, s1 = 0.0f;
  #pragma unroll
  for (int w = 0; w < 8; ++w) {
    s0 += part[w][2 * k][qe];
    s1 += part[w][2 * k + 1][qe];
  }
  const int bb = bq * 16 + 2 * k;
  float2 o = make_float2(s0 + bias[bb], s1 + bias[bb + 1]);
  *reinterpret_cast<float2*>(&out[(size_t)(qc * 64 + qe) * NBINS + bb]) = o;
}

// ---------- Fallback path (ws too small; works from raw inputs + 128KB pack) ----------
__global__ __launch_bounds__(256) void pack_fb(
    const float* __restrict__ probes,
    const float* __restrict__ wraw,
    const float* __restrict__ mw,
    float4* __restrict__ packed) {
  int idx = blockIdx.x * 256 + threadIdx.x;
  if (idx >= NBINS * NFREQ) return;
  int b = idx >> 6;
  int f = idx & 63;
  float pr = probes[b * HDIM + f];
  float pi = probes[b * HDIM + NFREQ + f];
  float x = wraw[b * NFREQ + f];
  float sp = fmaxf(x, 0.0f) + log1pf(expf(-fabsf(x)));
  packed[f * NBINS + b] = make_float4(pr, pi, -sp, mw[b * NFREQ + f]);
}

__global__ __launch_bounds__(256) void scorer_fallback(
    const float* __restrict__ Q,
    const float4* __restrict__ packed,
    const float* __restrict__ bias,
    float* __restrict__ out) {
  __shared__ float4 qlds[32][64];
  const int t = threadIdx.x;
  const int qbase = blockIdx.x * 32;
  {
    const int qi = t >> 3;
    const int f0 = (t & 7) * 8;
    const float* qp = Q + (size_t)(qbase + qi) * HDIM;
    float4 r0 = *reinterpret_cast<const float4*>(qp + f0);
    float4 r1 = *reinterpret_cast<const float4*>(qp + f0 + 4);
    float4 i0 = *reinterpret_cast<const float4*>(qp + NFREQ + f0);
    float4 i1 = *reinterpret_cast<const float4*>(qp + NFREQ + f0 + 4);
    float s = r0.x*r0.x + r0.y*r0.y + r0.z*r0.z + r0.w*r0.w
            + r1.x*r1.x + r1.y*r1.y + r1.z*r1.z + r1.w*r1.w
            + i0.x*i0.x + i0.y*i0.y + i0.z*i0.z + i0.w*i0.w
            + i1.x*i1.x + i1.y*i1.y + i1.z*i1.z + i1.w*i1.w;
    s += __shfl_xor(s, 1, 8);
    s += __shfl_xor(s, 2, 8);
    s += __shfl_xor(s, 4, 8);
    float inv = 1.0f / (__builtin_amdgcn_sqrtf(s) + EPSF);
    float re[8] = {r0.x, r0.y, r0.z, r0.w, r1.x, r1.y, r1.z, r1.w};
    float im[8] = {i0.x, i0.y, i0.z, i0.w, i1.x, i1.y, i1.z, i1.w};
    #pragma unroll
    for (int j = 0; j < 8; ++j) {
      float qr = re[j] * inv;
      float qim = im[j] * inv;
      float qm = __builtin_amdgcn_sqrtf(fmaf(qr, qr, fmaf(qim, qim, EPSF)));
      qlds[qi][f0 + j] = make_float4(qr, qim, qm, 0.0f);
    }
  }
  __syncthreads();
  const int w = t >> 6;
  const int lane = t & 63;
  const int b = (w & 1) * 64 + lane;
  const int qoff = (w >> 1) * 16;
  const float bb = bias[b];
  float acc[16];
  #pragma unroll
  for (int q = 0; q < 16; ++q) acc[q] = 0.0f;
  #pragma unroll
  for (int fc = 0; fc < 4; ++fc) {
    float4 c[16];
    #pragma unroll
    for (int fi = 0; fi < 16; ++fi)
      c[fi] = packed[(fc * 16 + fi) * NBINS + b];
    #pragma unroll 4
    for (int fi = 0; fi < 16; ++fi) {
      #pragma unroll
      for (int q = 0; q < 16; ++q) {
        float4 qv = qlds[qoff + q][fc * 16 + fi];
        float er = c[fi].x - qv.x;
        float ei = c[fi].y - qv.y;
        float d2 = fmaf(er, er, EPSF);
        d2 = fmaf(ei, ei, d2);
        float d = __builtin_amdgcn_sqrtf(d2);
        acc[q] = fmaf(d, c[fi].z, acc[q]);
        acc[q] = fmaf(qv.z, c[fi].w, acc[q]);
      }
    }
  }
  #pragma unroll
  for (int q = 0; q < 16; ++q)
    out[(size_t)(qbase + qoff + q) * NBINS + b] = acc[q] + bb;
}

extern "C" void kernel_launch(void* const* d_in, const int* in_sizes, int n_in,
                              void* d_out, int out_size, void* d_ws, size_t ws_size,
                              hipStream_t stream) {
  const float* Q      = (const float*)d_in[0];
  const float* probes = (const float*)d_in[1];
  const float* wraw   = (const float*)d_in[2];
  const float* mw     = (const float*)d_in[3];
  const float* bias   = (const float*)d_in[4];
  float* out = (float*)d_out;

  if (ws_size >= WS_NEEDED) {
    float4* probeT = (float4*)((char*)d_ws + PT_OFF);
    float* QRp = (float*)((char*)d_ws + QR_OFF);
    float* QIp = (float*)((char*)d_ws + QI_OFF);
    float* QMp = (float*)((char*)d_ws + QM_OFF);
    prologue6<<<QN_BLOCKS + PACK_BLOCKS, 256, 0, stream>>>(
        Q, probes, wraw, mw, probeT, QRp, QIp, QMp);
    scorer6<<<256 * 8, 512, 0, stream>>>(probeT, QRp, QIp, QMp, bias, out);
  } else {
    float4* packed = (float4*)d_ws;  // 128 KiB
    pack_fb<<<PACK_BLOCKS, 256, 0, stream>>>(probes, wraw, mw, packed);
    scorer_fallback<<<NQ / 32, 256, 0, stream>>>(Q, packed, bias, out);
  }
}

// Round 7
// 40.630 us; speedup vs baseline: 1.1197x; 1.1197x over previous
//
#include <hip/hip_runtime.h>

#define NBINS 128
#define NFREQ 64
#define HDIM 128
#define NQ 16384
#define EPSF 1e-8f

typedef float v2f __attribute__((ext_vector_type(2)));

__device__ __forceinline__ v2f pk_add(v2f a, v2f b) {
  v2f r;
  asm("v_pk_add_f32 %0, %1, %2" : "=v"(r) : "v"(a), "v"(b));
  return r;
}
__device__ __forceinline__ v2f pk_fma(v2f a, v2f b, v2f c) {
  v2f r;
  asm("v_pk_fma_f32 %0, %1, %2, %3" : "=v"(r) : "v"(a), "v"(b), "v"(c));
  return r;
}

// d_ws layout:
//   [0, 128 KiB)  : 4 probe planes (PR, PI, PW=-softplus(w), PM=mw), 32 KiB each.
//                   Plane element: float4 at [(fc*2 + bc)*64 + b0], component f&3,
//                   holding value for bin b = bc*64+b0, freq f = fc*4 + (f&3).
//   [128 KiB, +3 MiB) : Qb — per query 192 B: [fc(16)] x {nqr[4], nqi[4], qm[4]}
//                   (nqr/nqi are NEGATED normalized components; qm per-freq magnitude)
#define PLANE_FLOATS (NBINS * NFREQ)          // 8192 floats = 32 KiB
#define QB_OFF (128 * 1024)
#define QB_STRIDE 192                          // floats per query
#define WS_NEEDED ((size_t)QB_OFF + (size_t)NQ * QB_STRIDE * 4)

#define QN_BLOCKS (NQ / 64)                       // 256 blocks, 64 queries each
#define PACK_BLOCKS ((NBINS * NFREQ + 255) / 256) // 32 blocks

// ---------- Fused prologue: Q-normalize (blocks 0..255) + probe pack (rest) ----------
__global__ __launch_bounds__(256) void prologue7(
    const float* __restrict__ Q,
    const float* __restrict__ probes,
    const float* __restrict__ wraw,
    const float* __restrict__ mw,
    float* __restrict__ planes,   // PR|PI|PW|PM
    float* __restrict__ Qb) {
  const int blk = blockIdx.x;
  const int t = threadIdx.x;
  if (blk < QN_BLOCKS) {
    const int l = t & 3;                 // 4 lanes/query; lane l owns freqs [16l,16l+16)
    const int q = blk * 64 + (t >> 2);
    const float* qp = Q + (size_t)q * HDIM;
    float re[16], im[16];
    #pragma unroll
    for (int k = 0; k < 4; ++k) {
      *reinterpret_cast<float4*>(&re[k * 4]) =
          *reinterpret_cast<const float4*>(qp + 16 * l + k * 4);
      *reinterpret_cast<float4*>(&im[k * 4]) =
          *reinterpret_cast<const float4*>(qp + NFREQ + 16 * l + k * 4);
    }
    float s = 0.0f;
    #pragma unroll
    for (int k = 0; k < 16; ++k) {
      s = fmaf(re[k], re[k], s);
      s = fmaf(im[k], im[k], s);
    }
    s += __shfl_xor(s, 1, 4);
    s += __shfl_xor(s, 2, 4);
    const float inv = 1.0f / (__builtin_amdgcn_sqrtf(s) + EPSF);
    float4* qb4 = reinterpret_cast<float4*>(Qb + (size_t)q * QB_STRIDE);
    #pragma unroll
    for (int cc = 0; cc < 4; ++cc) {
      const int fc = 4 * l + cc;         // freq chunk of 4
      float nqr[4], nqi[4], qm[4];
      #pragma unroll
      for (int j = 0; j < 4; ++j) {
        const int k = cc * 4 + j;
        const float qr = re[k] * inv;
        const float qi = im[k] * inv;
        nqr[j] = -qr;
        nqi[j] = -qi;
        qm[j] = __builtin_amdgcn_sqrtf(fmaf(qr, qr, fmaf(qi, qi, EPSF)));
      }
      qb4[fc * 3 + 0] = make_float4(nqr[0], nqr[1], nqr[2], nqr[3]);
      qb4[fc * 3 + 1] = make_float4(nqi[0], nqi[1], nqi[2], nqi[3]);
      qb4[fc * 3 + 2] = make_float4(qm[0], qm[1], qm[2], qm[3]);
    }
  } else {
    const int idx = (blk - QN_BLOCKS) * 256 + t;
    if (idx >= NBINS * NFREQ) return;
    const int b = idx >> 6;
    const int f = idx & 63;
    const float pr = probes[b * HDIM + f];
    const float pi = probes[b * HDIM + NFREQ + f];
    const float x = wraw[b * NFREQ + f];
    const float sp = fmaxf(x, 0.0f) + log1pf(expf(-fabsf(x)));  // stable softplus
    const float m = mw[b * NFREQ + f];
    const int fc = f >> 2, bc = b >> 6, b0 = b & 63, fo = f & 3;
    const size_t e = (size_t)(((fc * 2 + bc) * 64 + b0) * 4 + fo);
    planes[0 * PLANE_FLOATS + e] = pr;
    planes[1 * PLANE_FLOATS + e] = pi;
    planes[2 * PLANE_FLOATS + e] = -sp;
    planes[3 * PLANE_FLOATS + e] = m;
  }
}

// one packed step: 2 freqs x 1 bin-copy; all pairs natural (no duplication)
__device__ __forceinline__ v2f dstep(v2f cpr, v2f cpi, v2f cw, v2f cmw,
                                     v2f nqr, v2f nqi, v2f qm, v2f eps2, v2f acc) {
  v2f er = pk_add(cpr, nqr);
  v2f ei = pk_add(cpi, nqi);
  v2f d2 = pk_fma(er, er, eps2);
  d2 = pk_fma(ei, ei, d2);
  v2f d;
  d.x = __builtin_amdgcn_sqrtf(d2.x);
  d.y = __builtin_amdgcn_sqrtf(d2.y);
  acc = pk_fma(d, cw, acc);
  acc = pk_fma(qm, cmw, acc);
  return acc;
}

// ---------- Main: block = 16 q x 128 bins x 64 f; wave = 4 q; lane = bin-pair ----------
__global__ __launch_bounds__(256) void scorer7(
    const float* __restrict__ planes,
    const float* __restrict__ Qb,
    const float* __restrict__ bias,
    float* __restrict__ out) {
  __shared__ float4 qlds4[768];  // 12 KB: 16 q x 16 fc x 3 float4
  const int t = threadIdx.x;
  const int qblk = blockIdx.x * 16;

  // Stage 16 queries' Qb into LDS (coalesced float4)
  {
    const float4* src = reinterpret_cast<const float4*>(Qb + (size_t)qblk * QB_STRIDE);
    qlds4[t] = src[t];
    qlds4[t + 256] = src[t + 256];
    qlds4[t + 512] = src[t + 512];
  }
  __syncthreads();

  const int b0 = t & 63;
  const int w = __builtin_amdgcn_readfirstlane(t >> 6);
  const int q0 = w * 4;

  const float4* PR = reinterpret_cast<const float4*>(planes + 0 * PLANE_FLOATS);
  const float4* PI = reinterpret_cast<const float4*>(planes + 1 * PLANE_FLOATS);
  const float4* PW = reinterpret_cast<const float4*>(planes + 2 * PLANE_FLOATS);
  const float4* PM = reinterpret_cast<const float4*>(planes + 3 * PLANE_FLOATS);

  const v2f eps2 = {EPSF, EPSF};
  v2f acc[4][2];
  #pragma unroll
  for (int q = 0; q < 4; ++q) {
    acc[q][0] = (v2f){0.0f, 0.0f};
    acc[q][1] = (v2f){0.0f, 0.0f};
  }

  #pragma unroll 1
  for (int fc = 0; fc < 16; ++fc) {
    // Per-lane probe data for this 4-freq chunk, both bin-copies (b0, b0+64)
    const int pb = fc * 128 + b0;
    const float4 pr0 = PR[pb], pr1 = PR[pb + 64];
    const float4 pi0 = PI[pb], pi1 = PI[pb + 64];
    const float4 w0  = PW[pb], w1  = PW[pb + 64];
    const float4 m0  = PM[pb], m1  = PM[pb + 64];
    const v2f pr0a = {pr0.x, pr0.y}, pr0b = {pr0.z, pr0.w};
    const v2f pr1a = {pr1.x, pr1.y}, pr1b = {pr1.z, pr1.w};
    const v2f pi0a = {pi0.x, pi0.y}, pi0b = {pi0.z, pi0.w};
    const v2f pi1a = {pi1.x, pi1.y}, pi1b = {pi1.z, pi1.w};
    const v2f w0a = {w0.x, w0.y}, w0b = {w0.z, w0.w};
    const v2f w1a = {w1.x, w1.y}, w1b = {w1.z, w1.w};
    const v2f m0a = {m0.x, m0.y}, m0b = {m0.z, m0.w};
    const v2f m1a = {m1.x, m1.y}, m1b = {m1.z, m1.w};

    #pragma unroll
    for (int q = 0; q < 4; ++q) {
      const int qb = ((q0 + q) * 16 + fc) * 3;   // wave-uniform LDS index
      const float4 a0 = qlds4[qb + 0];   // nqr[4]
      const float4 a1 = qlds4[qb + 1];   // nqi[4]
      const float4 a2 = qlds4[qb + 2];   // qm[4]
      const v2f nqr_a = {a0.x, a0.y}, nqr_b = {a0.z, a0.w};
      const v2f nqi_a = {a1.x, a1.y}, nqi_b = {a1.z, a1.w};
      const v2f qm_a = {a2.x, a2.y}, qm_b = {a2.z, a2.w};
      // bin-copy 0 (bins b0), freq pairs a/b
      acc[q][0] = dstep(pr0a, pi0a, w0a, m0a, nqr_a, nqi_a, qm_a, eps2, acc[q][0]);
      acc[q][0] = dstep(pr0b, pi0b, w0b, m0b, nqr_b, nqi_b, qm_b, eps2, acc[q][0]);
      // bin-copy 1 (bins b0+64)
      acc[q][1] = dstep(pr1a, pi1a, w1a, m1a, nqr_a, nqi_a, qm_a, eps2, acc[q][1]);
      acc[q][1] = dstep(pr1b, pi1b, w1b, m1b, nqr_b, nqi_b, qm_b, eps2, acc[q][1]);
    }
  }

  const float bias0 = bias[b0];
  const float bias1 = bias[64 + b0];
  #pragma unroll
  for (int q = 0; q < 4; ++q) {
    const size_t row = (size_t)(qblk + q0 + q) * NBINS;
    out[row + b0]      = acc[q][0].x + acc[q][0].y + bias0;
    out[row + 64 + b0] = acc[q][1].x + acc[q][1].y + bias1;
  }
}

// ---------- Fallback path (ws too small; works from raw inputs + 128KB pack) ----------
__global__ __launch_bounds__(256) void pack_fb(
    const float* __restrict__ probes,
    const float* __restrict__ wraw,
    const float* __restrict__ mw,
    float4* __restrict__ packed) {
  int idx = blockIdx.x * 256 + threadIdx.x;
  if (idx >= NBINS * NFREQ) return;
  int b = idx >> 6;
  int f = idx & 63;
  float pr = probes[b * HDIM + f];
  float pi = probes[b * HDIM + NFREQ + f];
  float x = wraw[b * NFREQ + f];
  float sp = fmaxf(x, 0.0f) + log1pf(expf(-fabsf(x)));
  packed[f * NBINS + b] = make_float4(pr, pi, -sp, mw[b * NFREQ + f]);
}

__global__ __launch_bounds__(256) void scorer_fallback(
    const float* __restrict__ Q,
    const float4* __restrict__ packed,
    const float* __restrict__ bias,
    float* __restrict__ out) {
  __shared__ float4 qlds[32][64];
  const int t = threadIdx.x;
  const int qbase = blockIdx.x * 32;
  {
    const int qi = t >> 3;
    const int f0 = (t & 7) * 8;
    const float* qp = Q + (size_t)(qbase + qi) * HDIM;
    float4 r0 = *reinterpret_cast<const float4*>(qp + f0);
    float4 r1 = *reinterpret_cast<const float4*>(qp + f0 + 4);
    float4 i0 = *reinterpret_cast<const float4*>(qp + NFREQ + f0);
    float4 i1 = *reinterpret_cast<const float4*>(qp + NFREQ + f0 + 4);
    float s = r0.x*r0.x + r0.y*r0.y + r0.z*r0.z + r0.w*r0.w
            + r1.x*r1.x + r1.y*r1.y + r1.z*r1.z + r1.w*r1.w
            + i0.x*i0.x + i0.y*i0.y + i0.z*i0.z + i0.w*i0.w
            + i1.x*i1.x + i1.y*i1.y + i1.z*i1.z + i1.w*i1.w;
    s += __shfl_xor(s, 1, 8);
    s += __shfl_xor(s, 2, 8);
    s += __shfl_xor(s, 4, 8);
    float inv = 1.0f / (__builtin_amdgcn_sqrtf(s) + EPSF);
    float re[8] = {r0.x, r0.y, r0.z, r0.w, r1.x, r1.y, r1.z, r1.w};
    float im[8] = {i0.x, i0.y, i0.z, i0.w, i1.x, i1.y, i1.z, i1.w};
    #pragma unroll
    for (int j = 0; j < 8; ++j) {
      float qr = re[j] * inv;
      float qim = im[j] * inv;
      float qm = __builtin_amdgcn_sqrtf(fmaf(qr, qr, fmaf(qim, qim, EPSF)));
      qlds[qi][f0 + j] = make_float4(qr, qim, qm, 0.0f);
    }
  }
  __syncthreads();
  const int w = t >> 6;
  const int lane = t & 63;
  const int b = (w & 1) * 64 + lane;
  const int qoff = (w >> 1) * 16;
  const float bb = bias[b];
  float acc[16];
  #pragma unroll
  for (int q = 0; q < 16; ++q) acc[q] = 0.0f;
  #pragma unroll
  for (int fc = 0; fc < 4; ++fc) {
    float4 c[16];
    #pragma unroll
    for (int fi = 0; fi < 16; ++fi)
      c[fi] = packed[(fc * 16 + fi) * NBINS + b];
    #pragma unroll 4
    for (int fi = 0; fi < 16; ++fi) {
      #pragma unroll
      for (int q = 0; q < 16; ++q) {
        float4 qv = qlds[qoff + q][fc * 16 + fi];
        float er = c[fi].x - qv.x;
        float ei = c[fi].y - qv.y;
        float d2 = fmaf(er, er, EPSF);
        d2 = fmaf(ei, ei, d2);
        float d = __builtin_amdgcn_sqrtf(d2);
        acc[q] = fmaf(d, c[fi].z, acc[q]);
        acc[q] = fmaf(qv.z, c[fi].w, acc[q]);
      }
    }
  }
  #pragma unroll
  for (int q = 0; q < 16; ++q)
    out[(size_t)(qbase + qoff + q) * NBINS + b] = acc[q] + bb;
}

extern "C" void kernel_launch(void* const* d_in, const int* in_sizes, int n_in,
                              void* d_out, int out_size, void* d_ws, size_t ws_size,
                              hipStream_t stream) {
  const float* Q      = (const float*)d_in[0];
  const float* probes = (const float*)d_in[1];
  const float* wraw   = (const float*)d_in[2];
  const float* mw     = (const float*)d_in[3];
  const float* bias   = (const float*)d_in[4];
  float* out = (float*)d_out;

  if (ws_size >= WS_NEEDED) {
    float* planes = (float*)d_ws;
    float* Qb = (float*)((char*)d_ws + QB_OFF);
    prologue7<<<QN_BLOCKS + PACK_BLOCKS, 256, 0, stream>>>(
        Q, probes, wraw, mw, planes, Qb);
    scorer7<<<NQ / 16, 256, 0, stream>>>(planes, Qb, bias, out);
  } else {
    float4* packed = (float4*)d_ws;  // 128 KiB
    pack_fb<<<PACK_BLOCKS, 256, 0, stream>>>(probes, wraw, mw, packed);
    scorer_fallback<<<NQ / 32, 256, 0, stream>>>(Q, packed, bias, out);
  }
}

// Round 9
// 38.160 us; speedup vs baseline: 1.1922x; 1.0647x over previous
//
#include <hip/hip_runtime.h>

#define NBINS 128
#define NFREQ 64
#define HDIM 128
#define NQ 16384
#define EPSF 1e-8f

typedef _Float16 h2 __attribute__((ext_vector_type(2)));
#define B2(x) __builtin_bit_cast(h2, (x))
#define U32(x) __builtin_bit_cast(unsigned, (x))

__device__ __forceinline__ h2 cvt_pk(float a, float b) {
  return __builtin_bit_cast(h2, __builtin_amdgcn_cvt_pkrtz(a, b));
}

// d_ws layout (all f16-packed probe data, 64 KiB total):
//   EP[c][b][fj] : (pr,pi) h2 word; c=0..7 (8-freq chunk), b=0..127, fj=0..7
//                  word idx (c*128+b)*8+fj                       -> 32 KiB
//   WP[c][b][fp] : (-softplus(w) for freqs 2fp,2fp+1) h2 word    -> 16 KiB @ +8192 words
//   MP[c][b][fp] : (mw) h2 word                                  -> 16 KiB @ +12288 words
#define WS_NEEDED (64 * 1024)

// ---------- tiny probe-pack kernel (f16, RNE via scalar casts) ----------
__global__ __launch_bounds__(256) void pack8(
    const float* __restrict__ probes,
    const float* __restrict__ wraw,
    const float* __restrict__ mw,
    unsigned* __restrict__ ws) {
  const int id = blockIdx.x * 256 + threadIdx.x;  // 1024 threads: (c,b)
  if (id >= 1024) return;
  const int c = id >> 7, b = id & 127;
  const float* pb = probes + b * HDIM + c * 8;
  const float* wb = wraw + b * NFREQ + c * 8;
  const float* mb = mw + b * NFREQ + c * 8;
  float pr[8], pi[8], w[8], m[8];
  *reinterpret_cast<float4*>(&pr[0]) = *reinterpret_cast<const float4*>(pb);
  *reinterpret_cast<float4*>(&pr[4]) = *reinterpret_cast<const float4*>(pb + 4);
  *reinterpret_cast<float4*>(&pi[0]) = *reinterpret_cast<const float4*>(pb + NFREQ);
  *reinterpret_cast<float4*>(&pi[4]) = *reinterpret_cast<const float4*>(pb + NFREQ + 4);
  *reinterpret_cast<float4*>(&w[0])  = *reinterpret_cast<const float4*>(wb);
  *reinterpret_cast<float4*>(&w[4])  = *reinterpret_cast<const float4*>(wb + 4);
  *reinterpret_cast<float4*>(&m[0])  = *reinterpret_cast<const float4*>(mb);
  *reinterpret_cast<float4*>(&m[4])  = *reinterpret_cast<const float4*>(mb + 4);
  unsigned ep[8], wp[4], mp[4];
  #pragma unroll
  for (int j = 0; j < 8; ++j) {
    h2 v = {(_Float16)pr[j], (_Float16)pi[j]};
    ep[j] = U32(v);
  }
  #pragma unroll
  for (int k = 0; k < 4; ++k) {
    float w0 = w[2 * k], w1 = w[2 * k + 1];
    float n0 = -(fmaxf(w0, 0.0f) + log1pf(expf(-fabsf(w0))));  // -softplus
    float n1 = -(fmaxf(w1, 0.0f) + log1pf(expf(-fabsf(w1))));
    h2 vw = {(_Float16)n0, (_Float16)n1};
    h2 vm = {(_Float16)m[2 * k], (_Float16)m[2 * k + 1]};
    wp[k] = U32(vw);
    mp[k] = U32(vm);
  }
  unsigned* EP = ws + (size_t)(c * 128 + b) * 8;
  *reinterpret_cast<uint4*>(EP)     = make_uint4(ep[0], ep[1], ep[2], ep[3]);
  *reinterpret_cast<uint4*>(EP + 4) = make_uint4(ep[4], ep[5], ep[6], ep[7]);
  unsigned* WP = ws + 8192 + (size_t)(c * 128 + b) * 4;
  *reinterpret_cast<uint4*>(WP) = make_uint4(wp[0], wp[1], wp[2], wp[3]);
  unsigned* MP = ws + 12288 + (size_t)(c * 128 + b) * 4;
  *reinterpret_cast<uint4*>(MP) = make_uint4(mp[0], mp[1], mp[2], mp[3]);
}

// ---------- fused scorer: in-block Q-normalize + f16 inner loop ----------
// Block: 16 queries x 128 bins x 64 freqs. 4 waves; wave w owns queries w*4..w*4+3.
// Lane = bin b0 (and bin-copy b0+64). Probes per-lane f16 from ws (L1/L2-hot, half bytes
// of r7). Q broadcast via wave-uniform LDS b128 reads of f16-interleaved fragments
// (half the LDS-pipe cost of r7). Accumulation f32 via v_dot2_f32_f16.
__global__ __launch_bounds__(256) void scorer8(
    const float* __restrict__ Q,
    const unsigned* __restrict__ ws,
    const float* __restrict__ bias,
    float* __restrict__ out) {
  __shared__ __align__(16) unsigned qep[16 * 64];  // [q][c][fj] (nqr,nqi) h2 ; 4 KB
  __shared__ __align__(16) unsigned qqm[16 * 32];  // [q][c][fp] (qm0,qm1) h2 ; 2 KB
  const int t = threadIdx.x;
  const int qblk = blockIdx.x * 16;

  // ---- Phase 1: normalize this block's 16 queries into LDS (16 lanes/query) ----
  {
    const int q = t >> 4;          // 0..15
    const int sub = t & 15;        // freq chunk of 4: f = sub*4..sub*4+3
    const float* qp = Q + (size_t)(qblk + q) * HDIM;
    const float4 re = *reinterpret_cast<const float4*>(qp + sub * 4);
    const float4 im = *reinterpret_cast<const float4*>(qp + NFREQ + sub * 4);
    float s = re.x * re.x + re.y * re.y + re.z * re.z + re.w * re.w
            + im.x * im.x + im.y * im.y + im.z * im.z + im.w * im.w;
    s += __shfl_xor(s, 1, 16);
    s += __shfl_xor(s, 2, 16);
    s += __shfl_xor(s, 4, 16);
    s += __shfl_xor(s, 8, 16);
    const float inv = 1.0f / (__builtin_amdgcn_sqrtf(s) + EPSF);
    const float qr[4] = {re.x * inv, re.y * inv, re.z * inv, re.w * inv};
    const float qi[4] = {im.x * inv, im.y * inv, im.z * inv, im.w * inv};
    unsigned ew[4], mwd[2];
    float qm[4];
    #pragma unroll
    for (int k = 0; k < 4; ++k) {
      h2 v = {(_Float16)(-qr[k]), (_Float16)(-qi[k])};
      ew[k] = U32(v);
      qm[k] = __builtin_amdgcn_sqrtf(fmaf(qr[k], qr[k], fmaf(qi[k], qi[k], EPSF)));
    }
    {
      h2 v0 = {(_Float16)qm[0], (_Float16)qm[1]};
      h2 v1 = {(_Float16)qm[2], (_Float16)qm[3]};
      mwd[0] = U32(v0);
      mwd[1] = U32(v1);
    }
    // epair words land at [q][c=sub>>1][fj=(sub&1)*4 + k] == q*64 + sub*4 + k
    *reinterpret_cast<uint4*>(&qep[q * 64 + sub * 4]) =
        make_uint4(ew[0], ew[1], ew[2], ew[3]);
    // qm pair-words land at q*32 + sub*2 + {0,1}
    *reinterpret_cast<uint2*>(&qqm[q * 32 + sub * 2]) = make_uint2(mwd[0], mwd[1]);
  }
  __syncthreads();

  // ---- Phase 2: main loop ----
  const int lane = t & 63;
  const int w = __builtin_amdgcn_readfirstlane(t >> 6);
  const int q0 = w * 4;
  const unsigned* EP = ws;
  const unsigned* WP = ws + 8192;
  const unsigned* MP = ws + 12288;

  float dacc[4][2], macc[4][2];
  #pragma unroll
  for (int q = 0; q < 4; ++q) {
    dacc[q][0] = dacc[q][1] = 0.0f;
    macc[q][0] = macc[q][1] = 0.0f;
  }

  #pragma unroll 1
  for (int c = 0; c < 8; ++c) {
    // per-lane probe words for this 8-freq chunk, both bin-copies (8x dwordx4)
    const uint4 e0a = *reinterpret_cast<const uint4*>(EP + (size_t)(c * 128 + lane) * 8);
    const uint4 e0b = *reinterpret_cast<const uint4*>(EP + (size_t)(c * 128 + lane) * 8 + 4);
    const uint4 e1a = *reinterpret_cast<const uint4*>(EP + (size_t)(c * 128 + 64 + lane) * 8);
    const uint4 e1b = *reinterpret_cast<const uint4*>(EP + (size_t)(c * 128 + 64 + lane) * 8 + 4);
    const uint4 w0v = *reinterpret_cast<const uint4*>(WP + (size_t)(c * 128 + lane) * 4);
    const uint4 w1v = *reinterpret_cast<const uint4*>(WP + (size_t)(c * 128 + 64 + lane) * 4);
    const uint4 m0v = *reinterpret_cast<const uint4*>(MP + (size_t)(c * 128 + lane) * 4);
    const uint4 m1v = *reinterpret_cast<const uint4*>(MP + (size_t)(c * 128 + 64 + lane) * 4);
    const unsigned ep[2][8] = {
        {e0a.x, e0a.y, e0a.z, e0a.w, e0b.x, e0b.y, e0b.z, e0b.w},
        {e1a.x, e1a.y, e1a.z, e1a.w, e1b.x, e1b.y, e1b.z, e1b.w}};
    const unsigned wp[2][4] = {{w0v.x, w0v.y, w0v.z, w0v.w},
                               {w1v.x, w1v.y, w1v.z, w1v.w}};
    const unsigned mp[2][4] = {{m0v.x, m0v.y, m0v.z, m0v.w},
                               {m1v.x, m1v.y, m1v.z, m1v.w}};
    #pragma unroll
    for (int q = 0; q < 4; ++q) {
      const uint4 qa = *reinterpret_cast<const uint4*>(&qep[(q0 + q) * 64 + c * 8]);
      const uint4 qb = *reinterpret_cast<const uint4*>(&qep[(q0 + q) * 64 + c * 8 + 4]);
      const uint4 qm4 = *reinterpret_cast<const uint4*>(&qqm[(q0 + q) * 32 + c * 4]);
      const unsigned qe[8] = {qa.x, qa.y, qa.z, qa.w, qb.x, qb.y, qb.z, qb.w};
      const unsigned qmw[4] = {qm4.x, qm4.y, qm4.z, qm4.w};
      #pragma unroll
      for (int bc = 0; bc < 2; ++bc) {
        float da = dacc[q][bc], ma = macc[q][bc];
        #pragma unroll
        for (int fp = 0; fp < 4; ++fp) {
          h2 e0 = B2(ep[bc][2 * fp]) + B2(qe[2 * fp]);          // v_pk_add_f16
          h2 e1 = B2(ep[bc][2 * fp + 1]) + B2(qe[2 * fp + 1]);
          float d0 = __builtin_amdgcn_fdot2(e0, e0, EPSF, false);
          float d1 = __builtin_amdgcn_fdot2(e1, e1, EPSF, false);
          h2 dp = cvt_pk(__builtin_amdgcn_sqrtf(d0), __builtin_amdgcn_sqrtf(d1));
          da = __builtin_amdgcn_fdot2(dp, B2(wp[bc][fp]), da, false);
          ma = __builtin_amdgcn_fdot2(B2(qmw[fp]), B2(mp[bc][fp]), ma, false);
        }
        dacc[q][bc] = da;
        macc[q][bc] = ma;
      }
    }
  }

  // ---- Epilogue ----
  const float bias0 = bias[lane];
  const float bias1 = bias[64 + lane];
  #pragma unroll
  for (int q = 0; q < 4; ++q) {
    const size_t row = (size_t)(qblk + q0 + q) * NBINS;
    out[row + lane]      = dacc[q][0] + macc[q][0] + bias0;
    out[row + 64 + lane] = dacc[q][1] + macc[q][1] + bias1;
  }
}

extern "C" void kernel_launch(void* const* d_in, const int* in_sizes, int n_in,
                              void* d_out, int out_size, void* d_ws, size_t ws_size,
                              hipStream_t stream) {
  const float* Q      = (const float*)d_in[0];
  const float* probes = (const float*)d_in[1];
  const float* wraw   = (const float*)d_in[2];
  const float* mw     = (const float*)d_in[3];
  const float* bias   = (const float*)d_in[4];
  float* out = (float*)d_out;
  unsigned* ws = (unsigned*)d_ws;  // needs 64 KiB (ws has been 256 MiB every round)

  pack8<<<4, 256, 0, stream>>>(probes, wraw, mw, ws);
  scorer8<<<NQ / 16, 256, 0, stream>>>(Q, ws, bias, out);
}